// Round 3
// baseline (459.764 us; speedup 1.0000x reference)
//
#include <hip/hip_runtime.h>
#include <hip/hip_bf16.h>
#include <math.h>

// Problem constants (B,S,H,NH,HS) = (4,2048,1024,16,64)
#define B_  4
#define S_  2048
#define H_  1024
#define NH_ 16
#define HS_ 64

typedef __attribute__((ext_vector_type(8))) short bf16x8;
typedef __attribute__((ext_vector_type(4))) short s16x4;
typedef __attribute__((ext_vector_type(4))) float f32x4;
typedef __attribute__((ext_vector_type(4))) unsigned u32x4;

// softmax scale folded into q-projection: (1/sqrt(HS)) * log2(e)
#define QSCALE_ (0.125f * 1.44269504f)

__device__ __forceinline__ short f2bf(float f) {
    // round-to-nearest-even fp32 -> bf16 (finite inputs only)
    unsigned u = __builtin_bit_cast(unsigned, f);
    u += 0x7FFFu + ((u >> 16) & 1u);
    return (short)(u >> 16);
}

typedef __attribute__((address_space(3))) void lds_void;
typedef const __attribute__((address_space(1))) void g_void;
__device__ __forceinline__ void gl_lds16(const void* g, void* l) {
    __builtin_amdgcn_global_load_lds((g_void*)g, (lds_void*)l, 16, 0, 0);
}

// ---------------------------------------------------------------------------
// Fused fp32 -> bf16 convert for all 7 tensors. blockIdx.y selects tensor.
// ---------------------------------------------------------------------------
__global__ __launch_bounds__(256) void cvt_all_k(
    const float* __restrict__ a0, const float* __restrict__ a1,
    const float* __restrict__ a2, const float* __restrict__ w0,
    const float* __restrict__ w1, const float* __restrict__ w2,
    const float* __restrict__ w3,
    short* o0, short* o1, short* o2, short* o3, short* o4, short* o5, short* o6)
{
    const int y = blockIdx.y;
    const float* ins[7]  = {a0, a1, a2, w0, w1, w2, w3};
    short*       outs[7] = {o0, o1, o2, o3, o4, o5, o6};
    const int n8 = (y < 3) ? (int)((size_t)B_ * S_ * H_ / 8) : (int)((size_t)H_ * H_ / 8);
    const int i = blockIdx.x * 256 + threadIdx.x;
    if (i >= n8) return;
    const float4* p = (const float4*)ins[y] + (size_t)i * 2;
    float4 a = p[0], b = p[1];
    bf16x8 o;
    o[0] = f2bf(a.x); o[1] = f2bf(a.y); o[2] = f2bf(a.z); o[3] = f2bf(a.w);
    o[4] = f2bf(b.x); o[5] = f2bf(b.y); o[6] = f2bf(b.z); o[7] = f2bf(b.w);
    *(bf16x8*)(outs[y] + (size_t)i * 8) = o;
}

// ---------------------------------------------------------------------------
// Shared MFMA GEMM core: 128x128 tile, BK=64 (16 iters), 4 waves (2x2),
// wave = 64x64, K fixed at 1024. LDS 16 KB per matrix, global_load_lds
// width=16, XOR-swizzled chunks.
// ---------------------------------------------------------------------------
__device__ __forceinline__ void gemm_core(
    const short* __restrict__ A, const short* __restrict__ W,
    int m0, int n0, short* As, short* Ws, f32x4 acc[4][4])
{
    const int tid  = threadIdx.x;
    const int w    = tid >> 6;
    const int lane = tid & 63;
    const int l15  = lane & 15;
    const int q4   = lane >> 4;
    const int wm   = w >> 1;
    const int wn   = w & 1;
    const int K    = 1024;
    const int swz  = l15 & 7;

    const char* Abase = (const char*)A + (size_t)m0 * K * 2;
    const char* Wbase = (const char*)W + (size_t)n0 * K * 2;

    #pragma unroll
    for (int mi = 0; mi < 4; ++mi)
        #pragma unroll
        for (int ni = 0; ni < 4; ++ni)
            acc[mi][ni] = (f32x4){0.f, 0.f, 0.f, 0.f};

    for (int k0 = 0; k0 < K; k0 += 64) {
        __syncthreads();
        #pragma unroll
        for (int t = 0; t < 4; ++t) {
            const int ob  = t * 4096 + w * 1024;      // wave-uniform LDS base
            const int idx = t * 256 + w * 64 + lane;  // 16B-chunk 0..1023
            const int row = idx >> 3;
            const int sc  = (idx & 7) ^ (row & 7);    // swizzled source chunk
            gl_lds16(Abase + (size_t)row * (K * 2) + k0 * 2 + sc * 16, (char*)As + ob);
            gl_lds16(Wbase + (size_t)row * (K * 2) + k0 * 2 + sc * 16, (char*)Ws + ob);
        }
        __syncthreads();

        #pragma unroll
        for (int kh = 0; kh < 2; ++kh) {
            bf16x8 af[4], bf[4];
            #pragma unroll
            for (int mi = 0; mi < 4; ++mi)
                af[mi] = *(const bf16x8*)(As + (wm * 64 + mi * 16 + l15) * 64
                                             + (((kh * 4 + q4) ^ swz) * 8));
            #pragma unroll
            for (int ni = 0; ni < 4; ++ni)
                bf[ni] = *(const bf16x8*)(Ws + (wn * 64 + ni * 16 + l15) * 64
                                             + (((kh * 4 + q4) ^ swz) * 8));
            #pragma unroll
            for (int mi = 0; mi < 4; ++mi)
                #pragma unroll
                for (int ni = 0; ni < 4; ++ni)
                    acc[mi][ni] = __builtin_amdgcn_mfma_f32_16x16x32_bf16(
                        af[mi], bf[ni], acc[mi][ni], 0, 0, 0);
        }
    }
}

// ---------------------------------------------------------------------------
// Fused projection GEMMs: z=0 -> q (scatter [B*NH,S,HS], scaled by QSCALE_),
// z=1 -> k (same layout), z=2 -> vT = Wv @ value^T (transpose-scatter).
// ---------------------------------------------------------------------------
__global__ __launch_bounds__(256) void gemm_proj_k(
    const short* __restrict__ Aq, const short* __restrict__ Wqb,
    const float* __restrict__ bq, short* __restrict__ qb,
    const short* __restrict__ Ak, const short* __restrict__ Wkb,
    const float* __restrict__ bk, short* __restrict__ kb,
    const short* __restrict__ Wvb, const short* __restrict__ Av,
    const float* __restrict__ bv, short* __restrict__ vtb)
{
    __shared__ short As[128 * 64];   // 16 KB
    __shared__ short Ws[128 * 64];   // 16 KB

    const int z = blockIdx.z;
    const short *A, *W; const float* bias; short* out;
    if (z == 0)      { A = Aq;  W = Wqb; bias = bq; out = qb;  }
    else if (z == 1) { A = Ak;  W = Wkb; bias = bk; out = kb;  }
    else             { A = Wvb; W = Av;  bias = bv; out = vtb; }
    const int m0 = (z == 2 ? blockIdx.y : blockIdx.x) * 128;
    const int n0 = (z == 2 ? blockIdx.x : blockIdx.y) * 128;

    f32x4 acc[4][4];
    gemm_core(A, W, m0, n0, As, Ws, acc);

    const int tid  = threadIdx.x;
    const int w    = tid >> 6;
    const int lane = tid & 63;
    const int l15  = lane & 15;
    const int q4   = lane >> 4;
    const int wm   = w >> 1;
    const int wn   = w & 1;

    #pragma unroll
    for (int mi = 0; mi < 4; ++mi) {
        #pragma unroll
        for (int r = 0; r < 4; ++r) {
            const int m = m0 + wm * 64 + mi * 16 + q4 * 4 + r;
            #pragma unroll
            for (int ni = 0; ni < 4; ++ni) {
                const int n = n0 + wn * 64 + ni * 16 + l15;
                float v = acc[mi][ni][r] + bias[z == 2 ? m : n];
                if (z == 0) v *= QSCALE_;   // fold softmax scale into q
                if (z != 2) {
                    const int b = m >> 11, s = m & (S_ - 1);
                    const int h = n >> 6,  d = n & (HS_ - 1);
                    out[(((size_t)b * NH_ + h) * S_ + s) * HS_ + d] = f2bf(v);
                } else {
                    const int b = n >> 11, s = n & (S_ - 1);
                    const int h = m >> 6,  d = m & (HS_ - 1);
                    out[(((size_t)b * NH_ + h) * HS_ + d) * S_ + s] = f2bf(v);
                }
            }
        }
    }
}

// ---------------------------------------------------------------------------
// Output-projection GEMM: fp32 row-major out = ctx @ Wo^T + bo
// ---------------------------------------------------------------------------
__global__ __launch_bounds__(256) void gemm_out_k(
    const short* __restrict__ A, const short* __restrict__ W,
    const float* __restrict__ bias, float* __restrict__ Cout)
{
    __shared__ short As[128 * 64];
    __shared__ short Ws[128 * 64];
    const int m0 = blockIdx.x * 128;
    const int n0 = blockIdx.y * 128;

    f32x4 acc[4][4];
    gemm_core(A, W, m0, n0, As, Ws, acc);

    const int tid  = threadIdx.x;
    const int w    = tid >> 6;
    const int lane = tid & 63;
    const int l15  = lane & 15;
    const int q4   = lane >> 4;
    const int wm   = w >> 1;
    const int wn   = w & 1;

    #pragma unroll
    for (int mi = 0; mi < 4; ++mi)
        #pragma unroll
        for (int r = 0; r < 4; ++r) {
            const int m = m0 + wm * 64 + mi * 16 + q4 * 4 + r;
            #pragma unroll
            for (int ni = 0; ni < 4; ++ni) {
                const int n = n0 + wn * 64 + ni * 16 + l15;
                Cout[(size_t)m * H_ + n] = acc[mi][ni][r] + bias[n];
            }
        }
}

// ---------------------------------------------------------------------------
// MFMA flash attention, round-10: barrier-free / LDS-free, per-wave tiles.
// Q,K in [B*NH,S,HS] bf16 (q pre-scaled by QSCALE_); V pre-transposed
// [B*NH,HS,S] bf16.
//
// Diagnosis r8/r9: K/V is L2-resident (FETCH 147->25 MB after XCD remap) but
// occupancy pinned ~18% by 50 KB LDS + lockstep barriers -> every pipe <20%
// real. LDS staging of L2-fit data is pure overhead (common-mistake #7).
//
// Design: each wave owns 32 q-rows, iterates 32-key blocks 0..qs fully
// independently. No __shared__, no __syncthreads.
//  * K fragments: direct 16B global loads (A-operand rows are contiguous).
//  * P stays in-register in its native S^T lane layout. The PV contraction
//    is invariant under a common permutation of k-slots of A and B, so
//    instead of redistributing P across lanes (LDS round-trip), V is
//    gathered with the SAME key order: k-slot (q4,j) holds key
//    sigma = (j>>2)*16 + q4*4 + (j&3); V-fragment = two 8B loads per db.
//  * exp2 via raw v_exp_f32 (scores pre-scaled into log2 domain).
//  * VGPR<=128 (launch_bounds 256,4) + LDS=0 -> whole 1024-block grid
//    resident (16 waves/CU). qt sequence chosen so stride-4 samples have
//    equal work sums (all-resident grids cannot rebalance).
// ---------------------------------------------------------------------------
__global__ __launch_bounds__(256, 4) void attn_mfma(
    const short* __restrict__ Q, const short* __restrict__ K,
    const short* __restrict__ VT, short* __restrict__ O)
{
    const int tid  = threadIdx.x;
    const int w    = tid >> 6;
    const int lane = tid & 63;
    const int l15  = lane & 15;
    const int q4   = lane >> 4;

    // XCD-chunked bijective remap: 1024 blocks, 8 XCDs, 128 blocks/chunk.
    // Within a chunk: head = pos&7 (8 heads per XCD -> 4 MB K/V = one L2),
    // qt = qtseq[pos>>3], chosen so {i, i+4, i+8, i+12} sums are equal
    // (CU c gets pos c, c+32, c+64, c+96 -> balanced work per CU).
    const int old = blockIdx.x;
    const int pos = old >> 3;            // 0..127 position within chunk
    const int xcd = old & 7;
    static const int qtseq[16] = {15,14,13,12, 0,1,2,3, 11,10,9,8, 4,5,6,7};
    const int bh = xcd * 8 + (pos & 7);
    const int qt = qtseq[pos >> 3];
    const int qs = qt * 4 + w;           // wave q-subtile (32 rows), 0..63

    const size_t base = (size_t)bh * S_ * HS_;
    const int b = bh >> 4;
    const int h = bh & 15;

    // Q fragments (B-operand of swapped QK^T): col=q=l15, k=d=kh*32+q4*8+j
    bf16x8 aQ[2][2];
    #pragma unroll
    for (int mi = 0; mi < 2; ++mi) {
        const int qrow = qs * 32 + mi * 16 + l15;
        #pragma unroll
        for (int kh = 0; kh < 2; ++kh)
            aQ[mi][kh] = *(const bf16x8*)(Q + base + (size_t)qrow * HS_ + kh * 32 + q4 * 8);
    }

    f32x4 accO[2][4];
    float lsum[2];
    #pragma unroll
    for (int mi = 0; mi < 2; ++mi) {
        #pragma unroll
        for (int db = 0; db < 4; ++db) accO[mi][db] = (f32x4){0.f, 0.f, 0.f, 0.f};
        lsum[mi] = 0.f;
    }

    const short* Kb = K  + base;
    const short* Vb = VT + base;

    for (int kb = 0; kb <= qs; ++kb) {
        // K fragments (A-operand): row=key=kb*32+nb*16+l15, k=d=kh*32+q4*8+j
        bf16x8 aK[2][2];
        #pragma unroll
        for (int nb = 0; nb < 2; ++nb)
            #pragma unroll
            for (int kh = 0; kh < 2; ++kh)
                aK[nb][kh] = *(const bf16x8*)(Kb + (size_t)(kb * 32 + nb * 16 + l15) * HS_
                                                 + kh * 32 + q4 * 8);
        // V fragments (B-operand of PV), key-reordered to match P lane layout:
        // k-slot (q4,j) = key (j>>2)*16 + q4*4 + (j&3)
        bf16x8 vf[4];
        #pragma unroll
        for (int db = 0; db < 4; ++db) {
            const short* vr = Vb + (size_t)(db * 16 + l15) * S_ + kb * 32;
            s16x4 vlo = *(const s16x4*)(vr + q4 * 4);
            s16x4 vhi = *(const s16x4*)(vr + 16 + q4 * 4);
            vf[db] = __builtin_shufflevector(vlo, vhi, 0, 1, 2, 3, 4, 5, 6, 7);
        }

        // S^T = K @ Q^T: lane (l15,q4) holds S[q=..+mi*16+l15][key=..+nb*16+q4*4+r]
        f32x4 sT[2][2];
        __builtin_amdgcn_s_setprio(1);
        #pragma unroll
        for (int mi = 0; mi < 2; ++mi)
            #pragma unroll
            for (int nb = 0; nb < 2; ++nb) {
                f32x4 a = (f32x4){0.f, 0.f, 0.f, 0.f};
                a = __builtin_amdgcn_mfma_f32_16x16x32_bf16(aK[nb][0], aQ[mi][0], a, 0, 0, 0);
                a = __builtin_amdgcn_mfma_f32_16x16x32_bf16(aK[nb][1], aQ[mi][1], a, 0, 0, 0);
                sT[mi][nb] = a;
            }
        __builtin_amdgcn_s_setprio(0);

        // causal mask: only the diagonal key-block needs it (wave-uniform)
        if (kb == qs) {
            #pragma unroll
            for (int mi = 0; mi < 2; ++mi)
                #pragma unroll
                for (int nb = 0; nb < 2; ++nb)
                    #pragma unroll
                    for (int r = 0; r < 4; ++r) {
                        const int kloc = nb * 16 + q4 * 4 + r;
                        const int qloc = mi * 16 + l15;
                        if (kloc > qloc) sT[mi][nb][r] = -INFINITY;
                    }
        }

        // p = exp2(s) (pre-scaled); accumulate l; pack A-fragment for PV.
        bf16x8 aP[2];
        #pragma unroll
        for (int mi = 0; mi < 2; ++mi) {
            float p[2][4];
            #pragma unroll
            for (int nb = 0; nb < 2; ++nb)
                #pragma unroll
                for (int r = 0; r < 4; ++r) {
                    float pv;
                    asm("v_exp_f32 %0, %1" : "=v"(pv) : "v"(sT[mi][nb][r]));
                    lsum[mi] += pv;       // exp2(-inf)=0 for masked
                    p[nb][r] = pv;
                }
            unsigned w0, w1, w2, w3;
            asm("v_cvt_pk_bf16_f32 %0, %1, %2" : "=v"(w0) : "v"(p[0][0]), "v"(p[0][1]));
            asm("v_cvt_pk_bf16_f32 %0, %1, %2" : "=v"(w1) : "v"(p[0][2]), "v"(p[0][3]));
            asm("v_cvt_pk_bf16_f32 %0, %1, %2" : "=v"(w2) : "v"(p[1][0]), "v"(p[1][1]));
            asm("v_cvt_pk_bf16_f32 %0, %1, %2" : "=v"(w3) : "v"(p[1][2]), "v"(p[1][3]));
            u32x4 pw; pw[0] = w0; pw[1] = w1; pw[2] = w2; pw[3] = w3;
            aP[mi] = __builtin_bit_cast(bf16x8, pw);
        }

        // O += P @ V  (k-slots of aP and vf share the same key permutation)
        __builtin_amdgcn_s_setprio(1);
        #pragma unroll
        for (int db = 0; db < 4; ++db)
            #pragma unroll
            for (int mi = 0; mi < 2; ++mi)
                accO[mi][db] = __builtin_amdgcn_mfma_f32_16x16x32_bf16(
                    aP[mi], vf[db], accO[mi][db], 0, 0, 0);
        __builtin_amdgcn_s_setprio(0);
    }

    // epilogue: lsum holds partial row-sum for q=l15; reduce across q4 groups.
    #pragma unroll
    for (int mi = 0; mi < 2; ++mi) {
        float ls = lsum[mi];
        ls += __shfl_xor(ls, 16);
        ls += __shfl_xor(ls, 32);
        // accO rows are q4*4+r; fetch that row's total from lane (q4*4+r)
        #pragma unroll
        for (int r = 0; r < 4; ++r) {
            const float inv = 1.f / __shfl(ls, q4 * 4 + r);
            const int orow = qs * 32 + mi * 16 + q4 * 4 + r;
            short* op = O + ((size_t)(b * S_ + orow)) * H_ + h * HS_;
            #pragma unroll
            for (int db = 0; db < 4; ++db)
                op[db * 16 + l15] = f2bf(accO[mi][db][r] * inv);
        }
    }
}

// ---------------------------------------------------------------------------
extern "C" void kernel_launch(void* const* d_in, const int* in_sizes, int n_in,
                              void* d_out, int out_size, void* d_ws, size_t ws_size,
                              hipStream_t stream)
{
    const float* query = (const float*)d_in[0];
    const float* key   = (const float*)d_in[1];
    const float* value = (const float*)d_in[2];
    // d_in[3] = causal_mask: unused (causality computed from indices)
    const float* Wq = (const float*)d_in[4];
    const float* bq = (const float*)d_in[5];
    const float* Wk = (const float*)d_in[6];
    const float* bk = (const float*)d_in[7];
    const float* Wv = (const float*)d_in[8];
    const float* bv = (const float*)d_in[9];
    const float* Wo = (const float*)d_in[10];
    const float* bo = (const float*)d_in[11];
    float* out = (float*)d_out;

    const size_t EA = (size_t)B_ * S_ * H_;   // 8388608 activation elems
    const size_t EW = (size_t)H_ * H_;        // 1048576 weight elems

    short* Aq  = (short*)d_ws;        // bf16 inputs [M,K]
    short* Ak  = Aq  + EA;
    short* Av  = Ak  + EA;
    short* Wqb = Av  + EA;            // bf16 weights [N,K]
    short* Wkb = Wqb + EW;
    short* Wvb = Wkb + EW;
    short* Wob = Wvb + EW;
    short* qb  = Wob + EW;            // bf16 q (pre-scaled) [B*NH, S, HS]
    short* kb  = qb  + EA;
    short* vtb = kb  + EA;            // bf16 v TRANSPOSED [B*NH, HS, S]
    short* cb  = vtb + EA;            // bf16 ctx [B, S, H]

    const int M = B_ * S_;   // 8192

    cvt_all_k<<<dim3((int)(EA / 8 / 256), 7), 256, 0, stream>>>(
        query, key, value, Wq, Wk, Wv, Wo,
        Aq, Ak, Av, Wqb, Wkb, Wvb, Wob);

    gemm_proj_k<<<dim3(M / 128, H_ / 128, 3), 256, 0, stream>>>(
        Aq, Wqb, bq, qb, Ak, Wkb, bk, kb, Wvb, Av, bv, vtb);

    attn_mfma<<<dim3(1024), 256, 0, stream>>>(qb, kb, vtb, cb);

    gemm_out_k<<<dim3(M / 128, H_ / 128), 256, 0, stream>>>(cb, Wob, bo, out);
}

// Round 4
// 458.762 us; speedup vs baseline: 1.0022x; 1.0022x over previous
//
#include <hip/hip_runtime.h>
#include <hip/hip_bf16.h>
#include <math.h>

// Problem constants (B,S,H,NH,HS) = (4,2048,1024,16,64)
#define B_  4
#define S_  2048
#define H_  1024
#define NH_ 16
#define HS_ 64

typedef __attribute__((ext_vector_type(8))) short bf16x8;
typedef __attribute__((ext_vector_type(4))) short s16x4;
typedef __attribute__((ext_vector_type(4))) float f32x4;
typedef __attribute__((ext_vector_type(4))) unsigned u32x4;

// softmax scale folded into q-projection: (1/sqrt(HS)) * log2(e)
#define QSCALE_ (0.125f * 1.44269504f)

__device__ __forceinline__ short f2bf(float f) {
    // round-to-nearest-even fp32 -> bf16 (finite inputs only)
    unsigned u = __builtin_bit_cast(unsigned, f);
    u += 0x7FFFu + ((u >> 16) & 1u);
    return (short)(u >> 16);
}

typedef __attribute__((address_space(3))) void lds_void;
typedef const __attribute__((address_space(1))) void g_void;
__device__ __forceinline__ void gl_lds16(const void* g, void* l) {
    __builtin_amdgcn_global_load_lds((g_void*)g, (lds_void*)l, 16, 0, 0);
}

// ---------------------------------------------------------------------------
// Fused fp32 -> bf16 convert for all 7 tensors. blockIdx.y selects tensor.
// ---------------------------------------------------------------------------
__global__ __launch_bounds__(256) void cvt_all_k(
    const float* __restrict__ a0, const float* __restrict__ a1,
    const float* __restrict__ a2, const float* __restrict__ w0,
    const float* __restrict__ w1, const float* __restrict__ w2,
    const float* __restrict__ w3,
    short* o0, short* o1, short* o2, short* o3, short* o4, short* o5, short* o6)
{
    const int y = blockIdx.y;
    const float* ins[7]  = {a0, a1, a2, w0, w1, w2, w3};
    short*       outs[7] = {o0, o1, o2, o3, o4, o5, o6};
    const int n8 = (y < 3) ? (int)((size_t)B_ * S_ * H_ / 8) : (int)((size_t)H_ * H_ / 8);
    const int i = blockIdx.x * 256 + threadIdx.x;
    if (i >= n8) return;
    const float4* p = (const float4*)ins[y] + (size_t)i * 2;
    float4 a = p[0], b = p[1];
    bf16x8 o;
    o[0] = f2bf(a.x); o[1] = f2bf(a.y); o[2] = f2bf(a.z); o[3] = f2bf(a.w);
    o[4] = f2bf(b.x); o[5] = f2bf(b.y); o[6] = f2bf(b.z); o[7] = f2bf(b.w);
    *(bf16x8*)(outs[y] + (size_t)i * 8) = o;
}

// ---------------------------------------------------------------------------
// Shared MFMA GEMM core: 128x128 tile, BK=64 (16 iters), 4 waves (2x2),
// wave = 64x64, K fixed at 1024. LDS 16 KB per matrix, global_load_lds
// width=16, XOR-swizzled chunks.
// ---------------------------------------------------------------------------
__device__ __forceinline__ void gemm_core(
    const short* __restrict__ A, const short* __restrict__ W,
    int m0, int n0, short* As, short* Ws, f32x4 acc[4][4])
{
    const int tid  = threadIdx.x;
    const int w    = tid >> 6;
    const int lane = tid & 63;
    const int l15  = lane & 15;
    const int q4   = lane >> 4;
    const int wm   = w >> 1;
    const int wn   = w & 1;
    const int K    = 1024;
    const int swz  = l15 & 7;

    const char* Abase = (const char*)A + (size_t)m0 * K * 2;
    const char* Wbase = (const char*)W + (size_t)n0 * K * 2;

    #pragma unroll
    for (int mi = 0; mi < 4; ++mi)
        #pragma unroll
        for (int ni = 0; ni < 4; ++ni)
            acc[mi][ni] = (f32x4){0.f, 0.f, 0.f, 0.f};

    for (int k0 = 0; k0 < K; k0 += 64) {
        __syncthreads();
        #pragma unroll
        for (int t = 0; t < 4; ++t) {
            const int ob  = t * 4096 + w * 1024;      // wave-uniform LDS base
            const int idx = t * 256 + w * 64 + lane;  // 16B-chunk 0..1023
            const int row = idx >> 3;
            const int sc  = (idx & 7) ^ (row & 7);    // swizzled source chunk
            gl_lds16(Abase + (size_t)row * (K * 2) + k0 * 2 + sc * 16, (char*)As + ob);
            gl_lds16(Wbase + (size_t)row * (K * 2) + k0 * 2 + sc * 16, (char*)Ws + ob);
        }
        __syncthreads();

        #pragma unroll
        for (int kh = 0; kh < 2; ++kh) {
            bf16x8 af[4], bf[4];
            #pragma unroll
            for (int mi = 0; mi < 4; ++mi)
                af[mi] = *(const bf16x8*)(As + (wm * 64 + mi * 16 + l15) * 64
                                             + (((kh * 4 + q4) ^ swz) * 8));
            #pragma unroll
            for (int ni = 0; ni < 4; ++ni)
                bf[ni] = *(const bf16x8*)(Ws + (wn * 64 + ni * 16 + l15) * 64
                                             + (((kh * 4 + q4) ^ swz) * 8));
            #pragma unroll
            for (int mi = 0; mi < 4; ++mi)
                #pragma unroll
                for (int ni = 0; ni < 4; ++ni)
                    acc[mi][ni] = __builtin_amdgcn_mfma_f32_16x16x32_bf16(
                        af[mi], bf[ni], acc[mi][ni], 0, 0, 0);
        }
    }
}

// ---------------------------------------------------------------------------
// Fused projection GEMMs: z=0 -> q (scatter [B*NH,S,HS], scaled by QSCALE_),
// z=1 -> k (same layout), z=2 -> vT = Wv @ value^T (transpose-scatter).
// ---------------------------------------------------------------------------
__global__ __launch_bounds__(256) void gemm_proj_k(
    const short* __restrict__ Aq, const short* __restrict__ Wqb,
    const float* __restrict__ bq, short* __restrict__ qb,
    const short* __restrict__ Ak, const short* __restrict__ Wkb,
    const float* __restrict__ bk, short* __restrict__ kb,
    const short* __restrict__ Wvb, const short* __restrict__ Av,
    const float* __restrict__ bv, short* __restrict__ vtb)
{
    __shared__ short As[128 * 64];   // 16 KB
    __shared__ short Ws[128 * 64];   // 16 KB

    const int z = blockIdx.z;
    const short *A, *W; const float* bias; short* out;
    if (z == 0)      { A = Aq;  W = Wqb; bias = bq; out = qb;  }
    else if (z == 1) { A = Ak;  W = Wkb; bias = bk; out = kb;  }
    else             { A = Wvb; W = Av;  bias = bv; out = vtb; }
    const int m0 = (z == 2 ? blockIdx.y : blockIdx.x) * 128;
    const int n0 = (z == 2 ? blockIdx.x : blockIdx.y) * 128;

    f32x4 acc[4][4];
    gemm_core(A, W, m0, n0, As, Ws, acc);

    const int tid  = threadIdx.x;
    const int w    = tid >> 6;
    const int lane = tid & 63;
    const int l15  = lane & 15;
    const int q4   = lane >> 4;
    const int wm   = w >> 1;
    const int wn   = w & 1;

    #pragma unroll
    for (int mi = 0; mi < 4; ++mi) {
        #pragma unroll
        for (int r = 0; r < 4; ++r) {
            const int m = m0 + wm * 64 + mi * 16 + q4 * 4 + r;
            #pragma unroll
            for (int ni = 0; ni < 4; ++ni) {
                const int n = n0 + wn * 64 + ni * 16 + l15;
                float v = acc[mi][ni][r] + bias[z == 2 ? m : n];
                if (z == 0) v *= QSCALE_;   // fold softmax scale into q
                if (z != 2) {
                    const int b = m >> 11, s = m & (S_ - 1);
                    const int h = n >> 6,  d = n & (HS_ - 1);
                    out[(((size_t)b * NH_ + h) * S_ + s) * HS_ + d] = f2bf(v);
                } else {
                    const int b = n >> 11, s = n & (S_ - 1);
                    const int h = m >> 6,  d = m & (HS_ - 1);
                    out[(((size_t)b * NH_ + h) * HS_ + d) * S_ + s] = f2bf(v);
                }
            }
        }
    }
}

// ---------------------------------------------------------------------------
// Output-projection GEMM: fp32 row-major out = ctx @ Wo^T + bo
// ---------------------------------------------------------------------------
__global__ __launch_bounds__(256) void gemm_out_k(
    const short* __restrict__ A, const short* __restrict__ W,
    const float* __restrict__ bias, float* __restrict__ Cout)
{
    __shared__ short As[128 * 64];
    __shared__ short Ws[128 * 64];
    const int m0 = blockIdx.x * 128;
    const int n0 = blockIdx.y * 128;

    f32x4 acc[4][4];
    gemm_core(A, W, m0, n0, As, Ws, acc);

    const int tid  = threadIdx.x;
    const int w    = tid >> 6;
    const int lane = tid & 63;
    const int l15  = lane & 15;
    const int q4   = lane >> 4;
    const int wm   = w >> 1;
    const int wn   = w & 1;

    #pragma unroll
    for (int mi = 0; mi < 4; ++mi)
        #pragma unroll
        for (int r = 0; r < 4; ++r) {
            const int m = m0 + wm * 64 + mi * 16 + q4 * 4 + r;
            #pragma unroll
            for (int ni = 0; ni < 4; ++ni) {
                const int n = n0 + wn * 64 + ni * 16 + l15;
                Cout[(size_t)m * H_ + n] = acc[mi][ni][r] + bias[n];
            }
        }
}

// ---------------------------------------------------------------------------
// MFMA flash attention, round-11: barrier-free / LDS-free + REGISTER
// SOFTWARE PIPELINE. Q,K in [B*NH,S,HS] bf16 (q pre-scaled by QSCALE_);
// V pre-transposed [B*NH,HS,S] bf16.
//
// Diagnosis r10: loads at top of each iteration, consumed immediately ->
// compiler waits vmcnt(0)-equivalent every 32-key step -> full L2 latency
// (~250cy; L1 thrashes since waves sweep different kb) exposed per iter;
// MfmaUtil 7.5%, VALUBusy 10.7%, 3.4K cy per iter-slot.
//
// Fix: prefetch tile kb+1's K/V fragments into a second register set while
// computing tile kb (the barrier-free analog of r8's LDS double-buffer).
// Prefetch is UNCONDITIONAL with clamped index (last iter re-loads its own
// tile) so the VMEM queue depth is constant and the compiler emits counted
// s_waitcnt vmcnt(12) instead of a conservative drain.
// VGPR ~145 -> launch_bounds(256,3); 768 blocks resident + 256 backfill.
// ---------------------------------------------------------------------------
__global__ __launch_bounds__(256, 3) void attn_mfma(
    const short* __restrict__ Q, const short* __restrict__ K,
    const short* __restrict__ VT, short* __restrict__ O)
{
    const int tid  = threadIdx.x;
    const int w    = tid >> 6;
    const int lane = tid & 63;
    const int l15  = lane & 15;
    const int q4   = lane >> 4;

    // XCD-chunked bijective remap: 1024 blocks, 8 XCDs, 128 blocks/chunk.
    // Within a chunk: head = pos&7 (8 heads per XCD -> 4 MB K/V = one L2),
    // qt = qtseq[pos>>3], chosen so stride-4 samples have equal work sums.
    const int old = blockIdx.x;
    const int pos = old >> 3;            // 0..127 position within chunk
    const int xcd = old & 7;
    static const int qtseq[16] = {15,14,13,12, 0,1,2,3, 11,10,9,8, 4,5,6,7};
    const int bh = xcd * 8 + (pos & 7);
    const int qt = qtseq[pos >> 3];
    const int qs = qt * 4 + w;           // wave q-subtile (32 rows), 0..63

    const size_t base = (size_t)bh * S_ * HS_;
    const int b = bh >> 4;
    const int h = bh & 15;

    // Q fragments (B-operand of swapped QK^T): col=q=l15, k=d=kh*32+q4*8+j
    bf16x8 aQ[2][2];
    #pragma unroll
    for (int mi = 0; mi < 2; ++mi) {
        const int qrow = qs * 32 + mi * 16 + l15;
        #pragma unroll
        for (int kh = 0; kh < 2; ++kh)
            aQ[mi][kh] = *(const bf16x8*)(Q + base + (size_t)qrow * HS_ + kh * 32 + q4 * 8);
    }

    f32x4 accO[2][4];
    float lsum[2];
    #pragma unroll
    for (int mi = 0; mi < 2; ++mi) {
        #pragma unroll
        for (int db = 0; db < 4; ++db) accO[mi][db] = (f32x4){0.f, 0.f, 0.f, 0.f};
        lsum[mi] = 0.f;
    }

    const short* Kb = K  + base;
    const short* Vb = VT + base;

    // fragment loaders -------------------------------------------------------
    // K (A-operand): row=key=kb*32+nb*16+l15, k=d=kh*32+q4*8+j
    // V (B-operand of PV), key-reordered to match P lane layout:
    //   k-slot (q4,j) = key (j>>2)*16 + q4*4 + (j&3)  -> two 8B loads per db
#define LOAD_K(dst, kb_)                                                        \
    do {                                                                        \
        _Pragma("unroll")                                                       \
        for (int nb = 0; nb < 2; ++nb)                                          \
            _Pragma("unroll")                                                   \
            for (int kh = 0; kh < 2; ++kh)                                      \
                dst[nb][kh] = *(const bf16x8*)(Kb + (size_t)((kb_) * 32 + nb * 16 + l15) * HS_ \
                                                  + kh * 32 + q4 * 8);          \
    } while (0)
#define LOAD_V(dst, kb_)                                                        \
    do {                                                                        \
        _Pragma("unroll")                                                       \
        for (int db = 0; db < 4; ++db) {                                        \
            const short* vr = Vb + (size_t)(db * 16 + l15) * S_ + (kb_) * 32;   \
            s16x4 vlo = *(const s16x4*)(vr + q4 * 4);                           \
            s16x4 vhi = *(const s16x4*)(vr + 16 + q4 * 4);                      \
            dst[db] = __builtin_shufflevector(vlo, vhi, 0, 1, 2, 3, 4, 5, 6, 7); \
        }                                                                       \
    } while (0)

    // prologue: tile 0 into the current buffers
    bf16x8 aK[2][2], vf[4];
    LOAD_K(aK, 0);
    LOAD_V(vf, 0);

    for (int kb = 0; kb <= qs; ++kb) {
        // prefetch next tile (clamped -> unconditional, constant VMEM depth)
        const int kbn = (kb < qs) ? (kb + 1) : qs;
        bf16x8 aKn[2][2], vfn[4];
        LOAD_K(aKn, kbn);
        LOAD_V(vfn, kbn);

        // S^T = K @ Q^T: lane (l15,q4) holds S[q=..+mi*16+l15][key=..+nb*16+q4*4+r]
        f32x4 sT[2][2];
        __builtin_amdgcn_s_setprio(1);
        #pragma unroll
        for (int mi = 0; mi < 2; ++mi)
            #pragma unroll
            for (int nb = 0; nb < 2; ++nb) {
                f32x4 a = (f32x4){0.f, 0.f, 0.f, 0.f};
                a = __builtin_amdgcn_mfma_f32_16x16x32_bf16(aK[nb][0], aQ[mi][0], a, 0, 0, 0);
                a = __builtin_amdgcn_mfma_f32_16x16x32_bf16(aK[nb][1], aQ[mi][1], a, 0, 0, 0);
                sT[mi][nb] = a;
            }
        __builtin_amdgcn_s_setprio(0);

        // causal mask: only the diagonal key-block needs it (wave-uniform)
        if (kb == qs) {
            #pragma unroll
            for (int mi = 0; mi < 2; ++mi)
                #pragma unroll
                for (int nb = 0; nb < 2; ++nb)
                    #pragma unroll
                    for (int r = 0; r < 4; ++r) {
                        const int kloc = nb * 16 + q4 * 4 + r;
                        const int qloc = mi * 16 + l15;
                        if (kloc > qloc) sT[mi][nb][r] = -INFINITY;
                    }
        }

        // p = exp2(s) (pre-scaled); accumulate l; pack A-fragment for PV.
        bf16x8 aP[2];
        #pragma unroll
        for (int mi = 0; mi < 2; ++mi) {
            float p[2][4];
            #pragma unroll
            for (int nb = 0; nb < 2; ++nb)
                #pragma unroll
                for (int r = 0; r < 4; ++r) {
                    float pv;
                    asm("v_exp_f32 %0, %1" : "=v"(pv) : "v"(sT[mi][nb][r]));
                    lsum[mi] += pv;       // exp2(-inf)=0 for masked
                    p[nb][r] = pv;
                }
            unsigned w0, w1, w2, w3;
            asm("v_cvt_pk_bf16_f32 %0, %1, %2" : "=v"(w0) : "v"(p[0][0]), "v"(p[0][1]));
            asm("v_cvt_pk_bf16_f32 %0, %1, %2" : "=v"(w1) : "v"(p[0][2]), "v"(p[0][3]));
            asm("v_cvt_pk_bf16_f32 %0, %1, %2" : "=v"(w2) : "v"(p[1][0]), "v"(p[1][1]));
            asm("v_cvt_pk_bf16_f32 %0, %1, %2" : "=v"(w3) : "v"(p[1][2]), "v"(p[1][3]));
            u32x4 pw; pw[0] = w0; pw[1] = w1; pw[2] = w2; pw[3] = w3;
            aP[mi] = __builtin_bit_cast(bf16x8, pw);
        }

        // O += P @ V  (k-slots of aP and vf share the same key permutation)
        __builtin_amdgcn_s_setprio(1);
        #pragma unroll
        for (int db = 0; db < 4; ++db)
            #pragma unroll
            for (int mi = 0; mi < 2; ++mi)
                accO[mi][db] = __builtin_amdgcn_mfma_f32_16x16x32_bf16(
                    aP[mi], vf[db], accO[mi][db], 0, 0, 0);
        __builtin_amdgcn_s_setprio(0);

        // rotate buffers (register renames; no memory traffic)
        #pragma unroll
        for (int nb = 0; nb < 2; ++nb)
            #pragma unroll
            for (int kh = 0; kh < 2; ++kh)
                aK[nb][kh] = aKn[nb][kh];
        #pragma unroll
        for (int db = 0; db < 4; ++db)
            vf[db] = vfn[db];
    }
#undef LOAD_K
#undef LOAD_V

    // epilogue: lsum holds partial row-sum for q=l15; reduce across q4 groups.
    #pragma unroll
    for (int mi = 0; mi < 2; ++mi) {
        float ls = lsum[mi];
        ls += __shfl_xor(ls, 16);
        ls += __shfl_xor(ls, 32);
        // accO rows are q4*4+r; fetch that row's total from lane (q4*4+r)
        #pragma unroll
        for (int r = 0; r < 4; ++r) {
            const float inv = 1.f / __shfl(ls, q4 * 4 + r);
            const int orow = qs * 32 + mi * 16 + q4 * 4 + r;
            short* op = O + ((size_t)(b * S_ + orow)) * H_ + h * HS_;
            #pragma unroll
            for (int db = 0; db < 4; ++db)
                op[db * 16 + l15] = f2bf(accO[mi][db][r] * inv);
        }
    }
}

// ---------------------------------------------------------------------------
extern "C" void kernel_launch(void* const* d_in, const int* in_sizes, int n_in,
                              void* d_out, int out_size, void* d_ws, size_t ws_size,
                              hipStream_t stream)
{
    const float* query = (const float*)d_in[0];
    const float* key   = (const float*)d_in[1];
    const float* value = (const float*)d_in[2];
    // d_in[3] = causal_mask: unused (causality computed from indices)
    const float* Wq = (const float*)d_in[4];
    const float* bq = (const float*)d_in[5];
    const float* Wk = (const float*)d_in[6];
    const float* bk = (const float*)d_in[7];
    const float* Wv = (const float*)d_in[8];
    const float* bv = (const float*)d_in[9];
    const float* Wo = (const float*)d_in[10];
    const float* bo = (const float*)d_in[11];
    float* out = (float*)d_out;

    const size_t EA = (size_t)B_ * S_ * H_;   // 8388608 activation elems
    const size_t EW = (size_t)H_ * H_;        // 1048576 weight elems

    short* Aq  = (short*)d_ws;        // bf16 inputs [M,K]
    short* Ak  = Aq  + EA;
    short* Av  = Ak  + EA;
    short* Wqb = Av  + EA;            // bf16 weights [N,K]
    short* Wkb = Wqb + EW;
    short* Wvb = Wkb + EW;
    short* Wob = Wvb + EW;
    short* qb  = Wob + EW;            // bf16 q (pre-scaled) [B*NH, S, HS]
    short* kb  = qb  + EA;
    short* vtb = kb  + EA;            // bf16 v TRANSPOSED [B*NH, HS, S]
    short* cb  = vtb + EA;            // bf16 ctx [B, S, H]

    const int M = B_ * S_;   // 8192

    cvt_all_k<<<dim3((int)(EA / 8 / 256), 7), 256, 0, stream>>>(
        query, key, value, Wq, Wk, Wv, Wo,
        Aq, Ak, Av, Wqb, Wkb, Wvb, Wob);

    gemm_proj_k<<<dim3(M / 128, H_ / 128, 3), 256, 0, stream>>>(
        Aq, Wqb, bq, qb, Ak, Wkb, bk, kb, Wvb, Av, bv, vtb);

    attn_mfma<<<dim3(1024), 256, 0, stream>>>(qb, kb, vtb, cb);

    gemm_out_k<<<dim3(M / 128, H_ / 128), 256, 0, stream>>>(cb, Wob, bo, out);
}

// Round 5
// 349.749 us; speedup vs baseline: 1.3146x; 1.3117x over previous
//
#include <hip/hip_runtime.h>
#include <hip/hip_bf16.h>
#include <math.h>

// Problem constants (B,S,H,NH,HS) = (4,2048,1024,16,64)
#define B_  4
#define S_  2048
#define H_  1024
#define NH_ 16
#define HS_ 64

typedef __attribute__((ext_vector_type(8))) short bf16x8;
typedef __attribute__((ext_vector_type(4))) short s16x4;
typedef __attribute__((ext_vector_type(4))) float f32x4;
typedef __attribute__((ext_vector_type(4))) unsigned u32x4;

// softmax scale folded into q-projection: (1/sqrt(HS)) * log2(e)
#define QSCALE_ (0.125f * 1.44269504f)

__device__ __forceinline__ short f2bf(float f) {
    // round-to-nearest-even fp32 -> bf16 (finite inputs only)
    unsigned u = __builtin_bit_cast(unsigned, f);
    u += 0x7FFFu + ((u >> 16) & 1u);
    return (short)(u >> 16);
}

typedef __attribute__((address_space(3))) void lds_void;
typedef const __attribute__((address_space(1))) void g_void;
__device__ __forceinline__ void gl_lds16(const void* g, void* l) {
    __builtin_amdgcn_global_load_lds((g_void*)g, (lds_void*)l, 16, 0, 0);
}

// XOR-swizzled LDS layout for 128 B row stride (8 x 16B chunks per row):
//   physical_chunk = logical_chunk ^ (row & 7)
// Writes: global_load_lds dest is contiguous (wave base + lane*16), so the
// SOURCE address selects chunk c ^ (r&7). Reads apply the same XOR.

// ---------------------------------------------------------------------------
// Fused fp32 -> bf16 convert for all 7 tensors. blockIdx.y selects tensor.
// ---------------------------------------------------------------------------
__global__ __launch_bounds__(256) void cvt_all_k(
    const float* __restrict__ a0, const float* __restrict__ a1,
    const float* __restrict__ a2, const float* __restrict__ w0,
    const float* __restrict__ w1, const float* __restrict__ w2,
    const float* __restrict__ w3,
    short* o0, short* o1, short* o2, short* o3, short* o4, short* o5, short* o6)
{
    const int y = blockIdx.y;
    const float* ins[7]  = {a0, a1, a2, w0, w1, w2, w3};
    short*       outs[7] = {o0, o1, o2, o3, o4, o5, o6};
    const int n8 = (y < 3) ? (int)((size_t)B_ * S_ * H_ / 8) : (int)((size_t)H_ * H_ / 8);
    const int i = blockIdx.x * 256 + threadIdx.x;
    if (i >= n8) return;
    const float4* p = (const float4*)ins[y] + (size_t)i * 2;
    float4 a = p[0], b = p[1];
    bf16x8 o;
    o[0] = f2bf(a.x); o[1] = f2bf(a.y); o[2] = f2bf(a.z); o[3] = f2bf(a.w);
    o[4] = f2bf(b.x); o[5] = f2bf(b.y); o[6] = f2bf(b.z); o[7] = f2bf(b.w);
    *(bf16x8*)(outs[y] + (size_t)i * 8) = o;
}

// ---------------------------------------------------------------------------
// Shared MFMA GEMM core: 128x128 tile, BK=64 (16 iters), 4 waves (2x2),
// wave = 64x64, K fixed at 1024. LDS 16 KB per matrix, global_load_lds
// width=16, XOR-swizzled chunks.
// ---------------------------------------------------------------------------
__device__ __forceinline__ void gemm_core(
    const short* __restrict__ A, const short* __restrict__ W,
    int m0, int n0, short* As, short* Ws, f32x4 acc[4][4])
{
    const int tid  = threadIdx.x;
    const int w    = tid >> 6;
    const int lane = tid & 63;
    const int l15  = lane & 15;
    const int q4   = lane >> 4;
    const int wm   = w >> 1;
    const int wn   = w & 1;
    const int K    = 1024;
    const int swz  = l15 & 7;

    const char* Abase = (const char*)A + (size_t)m0 * K * 2;
    const char* Wbase = (const char*)W + (size_t)n0 * K * 2;

    #pragma unroll
    for (int mi = 0; mi < 4; ++mi)
        #pragma unroll
        for (int ni = 0; ni < 4; ++ni)
            acc[mi][ni] = (f32x4){0.f, 0.f, 0.f, 0.f};

    for (int k0 = 0; k0 < K; k0 += 64) {
        __syncthreads();
        #pragma unroll
        for (int t = 0; t < 4; ++t) {
            const int ob  = t * 4096 + w * 1024;      // wave-uniform LDS base
            const int idx = t * 256 + w * 64 + lane;  // 16B-chunk 0..1023
            const int row = idx >> 3;
            const int sc  = (idx & 7) ^ (row & 7);    // swizzled source chunk
            gl_lds16(Abase + (size_t)row * (K * 2) + k0 * 2 + sc * 16, (char*)As + ob);
            gl_lds16(Wbase + (size_t)row * (K * 2) + k0 * 2 + sc * 16, (char*)Ws + ob);
        }
        __syncthreads();

        #pragma unroll
        for (int kh = 0; kh < 2; ++kh) {
            bf16x8 af[4], bf[4];
            #pragma unroll
            for (int mi = 0; mi < 4; ++mi)
                af[mi] = *(const bf16x8*)(As + (wm * 64 + mi * 16 + l15) * 64
                                             + (((kh * 4 + q4) ^ swz) * 8));
            #pragma unroll
            for (int ni = 0; ni < 4; ++ni)
                bf[ni] = *(const bf16x8*)(Ws + (wn * 64 + ni * 16 + l15) * 64
                                             + (((kh * 4 + q4) ^ swz) * 8));
            #pragma unroll
            for (int mi = 0; mi < 4; ++mi)
                #pragma unroll
                for (int ni = 0; ni < 4; ++ni)
                    acc[mi][ni] = __builtin_amdgcn_mfma_f32_16x16x32_bf16(
                        af[mi], bf[ni], acc[mi][ni], 0, 0, 0);
        }
    }
}

// ---------------------------------------------------------------------------
// Fused projection GEMMs: z=0 -> q (scatter [B*NH,S,HS], scaled by QSCALE_),
// z=1 -> k (same layout), z=2 -> vT = Wv @ value^T (transpose-scatter).
// ---------------------------------------------------------------------------
__global__ __launch_bounds__(256) void gemm_proj_k(
    const short* __restrict__ Aq, const short* __restrict__ Wqb,
    const float* __restrict__ bq, short* __restrict__ qb,
    const short* __restrict__ Ak, const short* __restrict__ Wkb,
    const float* __restrict__ bk, short* __restrict__ kb,
    const short* __restrict__ Wvb, const short* __restrict__ Av,
    const float* __restrict__ bv, short* __restrict__ vtb)
{
    __shared__ short As[128 * 64];   // 16 KB
    __shared__ short Ws[128 * 64];   // 16 KB

    const int z = blockIdx.z;
    const short *A, *W; const float* bias; short* out;
    if (z == 0)      { A = Aq;  W = Wqb; bias = bq; out = qb;  }
    else if (z == 1) { A = Ak;  W = Wkb; bias = bk; out = kb;  }
    else             { A = Wvb; W = Av;  bias = bv; out = vtb; }
    const int m0 = (z == 2 ? blockIdx.y : blockIdx.x) * 128;
    const int n0 = (z == 2 ? blockIdx.x : blockIdx.y) * 128;

    f32x4 acc[4][4];
    gemm_core(A, W, m0, n0, As, Ws, acc);

    const int tid  = threadIdx.x;
    const int w    = tid >> 6;
    const int lane = tid & 63;
    const int l15  = lane & 15;
    const int q4   = lane >> 4;
    const int wm   = w >> 1;
    const int wn   = w & 1;

    #pragma unroll
    for (int mi = 0; mi < 4; ++mi) {
        #pragma unroll
        for (int r = 0; r < 4; ++r) {
            const int m = m0 + wm * 64 + mi * 16 + q4 * 4 + r;
            #pragma unroll
            for (int ni = 0; ni < 4; ++ni) {
                const int n = n0 + wn * 64 + ni * 16 + l15;
                float v = acc[mi][ni][r] + bias[z == 2 ? m : n];
                if (z == 0) v *= QSCALE_;   // fold softmax scale into q
                if (z != 2) {
                    const int b = m >> 11, s = m & (S_ - 1);
                    const int h = n >> 6,  d = n & (HS_ - 1);
                    out[(((size_t)b * NH_ + h) * S_ + s) * HS_ + d] = f2bf(v);
                } else {
                    const int b = n >> 11, s = n & (S_ - 1);
                    const int h = m >> 6,  d = m & (HS_ - 1);
                    out[(((size_t)b * NH_ + h) * HS_ + d) * S_ + s] = f2bf(v);
                }
            }
        }
    }
}

// ---------------------------------------------------------------------------
// Output-projection GEMM: fp32 row-major out = ctx @ Wo^T + bo
// ---------------------------------------------------------------------------
__global__ __launch_bounds__(256) void gemm_out_k(
    const short* __restrict__ A, const short* __restrict__ W,
    const float* __restrict__ bias, float* __restrict__ Cout)
{
    __shared__ short As[128 * 64];
    __shared__ short Ws[128 * 64];
    const int m0 = blockIdx.x * 128;
    const int n0 = blockIdx.y * 128;

    f32x4 acc[4][4];
    gemm_core(A, W, m0, n0, As, Ws, acc);

    const int tid  = threadIdx.x;
    const int w    = tid >> 6;
    const int lane = tid & 63;
    const int l15  = lane & 15;
    const int q4   = lane >> 4;
    const int wm   = w >> 1;
    const int wn   = w & 1;

    #pragma unroll
    for (int mi = 0; mi < 4; ++mi)
        #pragma unroll
        for (int r = 0; r < 4; ++r) {
            const int m = m0 + wm * 64 + mi * 16 + q4 * 4 + r;
            #pragma unroll
            for (int ni = 0; ni < 4; ++ni) {
                const int n = n0 + wn * 64 + ni * 16 + l15;
                Cout[(size_t)m * H_ + n] = acc[mi][ni][r] + bias[n];
            }
        }
}

// ---------------------------------------------------------------------------
// MFMA flash attention, round-12: REVERT to the verified r1 skeleton
// (512 blocks x 2-pass pairing {bx,15-bx}, K/V double-buffered in LDS via
// global_load_lds, one __syncthreads per tile -- measured 107.5 us), with
// the numerically-verified slimmings from r2-r4 grafted in:
//  * P stays in registers (S^T lane layout). PV reads V from the swizzled
//    LDS tile with the KEY-PERMUTED b64 pattern so the contraction matches
//    P's native layout: k-slot (q4,j) = key hf*32 + (j>>2)*16 + q4*4 + (j&3).
//    Deletes the per-tile P write+wait+read LDS round-trip and 18 KB LDS.
//  * q pre-scaled by QSCALE_ in proj; p = v_exp_f32(s) directly.
//  * P packed via v_cvt_pk_bf16_f32; row-sum as scalar lsum + 2 shfl_xor.
// Lesson r3/r4: register-resident K/V (no LDS) exposes vmem latency per
// wave and lands at 185 us regardless of pipelining -- DMA->LDS staging is
// the right transport for this shape. Do not remove it again.
// ---------------------------------------------------------------------------
__global__ __launch_bounds__(256) void attn_mfma(
    const short* __restrict__ Q, const short* __restrict__ K,
    const short* __restrict__ VT, short* __restrict__ O)
{
    __shared__ short Ks[2][64 * 64];     // [slot][key][d]  8 KB/slot, swizzled
    __shared__ short Vt[2][64 * 64];     // [slot][d][key]  8 KB/slot, swizzled

    const int tid  = threadIdx.x;
    const int w    = tid >> 6;
    const int lane = tid & 63;
    const int l15  = lane & 15;
    const int q4   = lane >> 4;
    const int swz  = l15 & 7;
    const int bh   = blockIdx.y;
    const size_t base = (size_t)bh * S_ * HS_;
    const int b = bh >> 4;
    const int h = bh & 15;

    // stage kv-tile kt_ into LDS slot: async DMA, swizzled source chunks.
#define STAGE_KV(slot_, kt_)                                                      \
    do {                                                                          \
        _Pragma("unroll")                                                         \
        for (int t = 0; t < 2; ++t) {                                             \
            const int ob  = (slot_) * 8192 + t * 4096 + w * 1024;                 \
            const int idx = t * 256 + w * 64 + lane;   /* 16B-chunk 0..511 */     \
            const int r   = idx >> 3;                                             \
            const int sc  = (idx & 7) ^ (r & 7);       /* swizzled src chunk */   \
            gl_lds16(K + base + (size_t)((kt_) * 64 + r) * HS_ + sc * 8,          \
                     (char*)Ks + ob);                                             \
            gl_lds16(VT + base + (size_t)r * S_ + (kt_) * 64 + sc * 8,            \
                     (char*)Vt + ob);                                             \
        }                                                                         \
    } while (0)

    #pragma unroll 1
    for (int pass = 0; pass < 2; ++pass) {
        const int qt = pass ? (15 - blockIdx.x) : blockIdx.x;
        const int ktmax = 2 * qt + 1;

        // prologue: stage tile 0 into slot 0 (drained by the syncthreads below)
        STAGE_KV(0, 0);

        bf16x8 aQ[2][2];
        #pragma unroll
        for (int mi = 0; mi < 2; ++mi) {
            const int qrow = qt * 128 + w * 32 + mi * 16 + l15;
            #pragma unroll
            for (int kh = 0; kh < 2; ++kh)
                aQ[mi][kh] = *(const bf16x8*)(Q + base + (size_t)qrow * HS_ + kh * 32 + q4 * 8);
        }

        f32x4 accO[2][4];
        float lsum[2];
        #pragma unroll
        for (int mi = 0; mi < 2; ++mi) {
            #pragma unroll
            for (int db = 0; db < 4; ++db) accO[mi][db] = (f32x4){0.f, 0.f, 0.f, 0.f};
            lsum[mi] = 0.f;
        }

        __syncthreads();  // tile 0 resident

        for (int kt = 0; kt <= ktmax; ++kt) {
            const int cur = kt & 1;
            // issue next tile's loads NOW; they drain at this iter's barrier
            if (kt < ktmax) STAGE_KV(cur ^ 1, kt + 1);

            // S^T = K @ Q^T: lane (l15,q4) holds
            //   S[q = qt*128+w*32+mi*16+l15][key = kt*64+nb*16+q4*4+r]
            f32x4 sT[2][4];
            const short* KsBase = &Ks[cur][0];
            __builtin_amdgcn_s_setprio(1);
            #pragma unroll
            for (int nb = 0; nb < 4; ++nb) {
                const short* krow = KsBase + (nb * 16 + l15) * 64;
                bf16x8 k0 = *(const bf16x8*)(krow + ((q4 ^ swz) * 8));
                bf16x8 k1 = *(const bf16x8*)(krow + (((4 + q4) ^ swz) * 8));
                #pragma unroll
                for (int mi = 0; mi < 2; ++mi) {
                    f32x4 a = (f32x4){0.f, 0.f, 0.f, 0.f};
                    a = __builtin_amdgcn_mfma_f32_16x16x32_bf16(k0, aQ[mi][0], a, 0, 0, 0);
                    a = __builtin_amdgcn_mfma_f32_16x16x32_bf16(k1, aQ[mi][1], a, 0, 0, 0);
                    sT[mi][nb] = a;
                }
            }
            __builtin_amdgcn_s_setprio(0);

            // causal mask (wave-uniform trigger, last two tiles of the pass)
            if (kt >= 2 * qt) {
                #pragma unroll
                for (int mi = 0; mi < 2; ++mi) {
                    const int qrow = qt * 128 + w * 32 + mi * 16 + l15;
                    #pragma unroll
                    for (int nb = 0; nb < 4; ++nb)
                        #pragma unroll
                        for (int r = 0; r < 4; ++r) {
                            const int kj = kt * 64 + nb * 16 + q4 * 4 + r;
                            if (kj > qrow) sT[mi][nb][r] = -INFINITY;
                        }
                }
            }

            // p = exp2(s) (pre-scaled); accumulate l; pack PV A-fragments.
            // aP[mi][hf] holds keys hf*32 + sigma(q4,j), sigma matching the
            // permuted V reads below.
            bf16x8 aP[2][2];
            #pragma unroll
            for (int mi = 0; mi < 2; ++mi) {
                float p[4][4];
                #pragma unroll
                for (int nb = 0; nb < 4; ++nb)
                    #pragma unroll
                    for (int r = 0; r < 4; ++r) {
                        float pv;
                        asm("v_exp_f32 %0, %1" : "=v"(pv) : "v"(sT[mi][nb][r]));
                        lsum[mi] += pv;       // exp2(-inf)=0 for masked
                        p[nb][r] = pv;
                    }
                #pragma unroll
                for (int hf = 0; hf < 2; ++hf) {
                    unsigned w0, w1, w2, w3;
                    asm("v_cvt_pk_bf16_f32 %0, %1, %2" : "=v"(w0) : "v"(p[2*hf][0]),   "v"(p[2*hf][1]));
                    asm("v_cvt_pk_bf16_f32 %0, %1, %2" : "=v"(w1) : "v"(p[2*hf][2]),   "v"(p[2*hf][3]));
                    asm("v_cvt_pk_bf16_f32 %0, %1, %2" : "=v"(w2) : "v"(p[2*hf+1][0]), "v"(p[2*hf+1][1]));
                    asm("v_cvt_pk_bf16_f32 %0, %1, %2" : "=v"(w3) : "v"(p[2*hf+1][2]), "v"(p[2*hf+1][3]));
                    u32x4 pw; pw[0] = w0; pw[1] = w1; pw[2] = w2; pw[3] = w3;
                    aP[mi][hf] = __builtin_bit_cast(bf16x8, pw);
                }
            }

            // O += P @ V. V B-fragment read key-permuted from swizzled LDS:
            // for (db,hf): vlo = keys hf*32+q4*4+{0..3}  (logical chunk 4hf+(q4>>1)),
            //              vhi = keys hf*32+16+q4*4+{0..3} (chunk 4hf+2+(q4>>1)),
            // both at row db*16+l15 (swz = l15&7), byte-in-chunk 8*(q4&1).
            const short* VtBase = &Vt[cur][0];
            __builtin_amdgcn_s_setprio(1);
            #pragma unroll
            for (int db = 0; db < 4; ++db) {
                const short* vrow = VtBase + (db * 16 + l15) * 64;
                #pragma unroll
                for (int hf = 0; hf < 2; ++hf) {
                    const int lc0 = 4 * hf + (q4 >> 1);
                    const int lc1 = lc0 + 2;
                    s16x4 vlo = *(const s16x4*)(vrow + ((lc0 ^ swz) * 8) + 4 * (q4 & 1));
                    s16x4 vhi = *(const s16x4*)(vrow + ((lc1 ^ swz) * 8) + 4 * (q4 & 1));
                    bf16x8 vf = __builtin_shufflevector(vlo, vhi, 0, 1, 2, 3, 4, 5, 6, 7);
                    #pragma unroll
                    for (int mi = 0; mi < 2; ++mi)
                        accO[mi][db] = __builtin_amdgcn_mfma_f32_16x16x32_bf16(
                            aP[mi][hf], vf, accO[mi][db], 0, 0, 0);
                }
            }
            __builtin_amdgcn_s_setprio(0);

            // one barrier per tile: drains next-tile DMA (vmcnt 0) + protects
            // slot restage
            __syncthreads();
        }

        // epilogue: lsum holds partial row-sum for q-row (mi*16+l15);
        // reduce across the 4 q4-groups, then normalize + write.
        #pragma unroll
        for (int mi = 0; mi < 2; ++mi) {
            float ls = lsum[mi];
            ls += __shfl_xor(ls, 16);
            ls += __shfl_xor(ls, 32);
            // accO rows are q4*4+r; that row's total lives in lane (q4*4+r)
            #pragma unroll
            for (int r = 0; r < 4; ++r) {
                const float inv = 1.f / __shfl(ls, q4 * 4 + r);
                const int orow = qt * 128 + w * 32 + mi * 16 + q4 * 4 + r;
                short* op = O + ((size_t)(b * S_ + orow)) * H_ + h * HS_;
                #pragma unroll
                for (int db = 0; db < 4; ++db)
                    op[db * 16 + l15] = f2bf(accO[mi][db][r] * inv);
            }
        }
        // last loop iter ended in __syncthreads and the epilogue touches no
        // LDS, so pass 1's prologue STAGE is safe.
    }
#undef STAGE_KV
}

// ---------------------------------------------------------------------------
extern "C" void kernel_launch(void* const* d_in, const int* in_sizes, int n_in,
                              void* d_out, int out_size, void* d_ws, size_t ws_size,
                              hipStream_t stream)
{
    const float* query = (const float*)d_in[0];
    const float* key   = (const float*)d_in[1];
    const float* value = (const float*)d_in[2];
    // d_in[3] = causal_mask: unused (causality computed from indices)
    const float* Wq = (const float*)d_in[4];
    const float* bq = (const float*)d_in[5];
    const float* Wk = (const float*)d_in[6];
    const float* bk = (const float*)d_in[7];
    const float* Wv = (const float*)d_in[8];
    const float* bv = (const float*)d_in[9];
    const float* Wo = (const float*)d_in[10];
    const float* bo = (const float*)d_in[11];
    float* out = (float*)d_out;

    const size_t EA = (size_t)B_ * S_ * H_;   // 8388608 activation elems
    const size_t EW = (size_t)H_ * H_;        // 1048576 weight elems

    short* Aq  = (short*)d_ws;        // bf16 inputs [M,K]
    short* Ak  = Aq  + EA;
    short* Av  = Ak  + EA;
    short* Wqb = Av  + EA;            // bf16 weights [N,K]
    short* Wkb = Wqb + EW;
    short* Wvb = Wkb + EW;
    short* Wob = Wvb + EW;
    short* qb  = Wob + EW;            // bf16 q (pre-scaled) [B*NH, S, HS]
    short* kb  = qb  + EA;
    short* vtb = kb  + EA;            // bf16 v TRANSPOSED [B*NH, HS, S]
    short* cb  = vtb + EA;            // bf16 ctx [B, S, H]

    const int M = B_ * S_;   // 8192

    cvt_all_k<<<dim3((int)(EA / 8 / 256), 7), 256, 0, stream>>>(
        query, key, value, Wq, Wk, Wv, Wo,
        Aq, Ak, Av, Wqb, Wkb, Wvb, Wob);

    gemm_proj_k<<<dim3(M / 128, H_ / 128, 3), 256, 0, stream>>>(
        Aq, Wqb, bq, qb, Ak, Wkb, bk, kb, Wvb, Av, bv, vtb);

    attn_mfma<<<dim3(S_ / 256, B_ * NH_), 256, 0, stream>>>(qb, kb, vtb, cb);

    gemm_out_k<<<dim3(M / 128, H_ / 128), 256, 0, stream>>>(cb, Wob, bo, out);
}

// Round 7
// 318.065 us; speedup vs baseline: 1.4455x; 1.0996x over previous
//
#include <hip/hip_runtime.h>
#include <hip/hip_bf16.h>
#include <math.h>

// Problem constants (B,S,H,NH,HS) = (4,2048,1024,16,64)
#define B_  4
#define S_  2048
#define H_  1024
#define NH_ 16
#define HS_ 64

typedef __attribute__((ext_vector_type(8))) short bf16x8;
typedef __attribute__((ext_vector_type(4))) short s16x4;
typedef __attribute__((ext_vector_type(4))) float f32x4;
typedef __attribute__((ext_vector_type(4))) unsigned u32x4;

// softmax scale folded into q-projection: (1/sqrt(HS)) * log2(e)
#define QSCALE_ (0.125f * 1.44269504f)

__device__ __forceinline__ short f2bf(float f) {
    // round-to-nearest-even fp32 -> bf16 (finite inputs only)
    unsigned u = __builtin_bit_cast(unsigned, f);
    u += 0x7FFFu + ((u >> 16) & 1u);
    return (short)(u >> 16);
}

typedef __attribute__((address_space(3))) void lds_void;
typedef const __attribute__((address_space(1))) void g_void;
__device__ __forceinline__ void gl_lds16(const void* g, void* l) {
    __builtin_amdgcn_global_load_lds((g_void*)g, (lds_void*)l, 16, 0, 0);
}

// XOR-swizzled LDS layout for 128 B row stride (8 x 16B chunks per row):
//   physical_chunk = logical_chunk ^ (row & 7)
// Writes: global_load_lds dest is contiguous (wave base + lane*16), so the
// SOURCE address selects chunk c ^ (r&7). Reads apply the same XOR.

// ---------------------------------------------------------------------------
// Fused fp32 -> bf16 convert for all 7 tensors. blockIdx.y selects tensor.
// ---------------------------------------------------------------------------
__global__ __launch_bounds__(256) void cvt_all_k(
    const float* __restrict__ a0, const float* __restrict__ a1,
    const float* __restrict__ a2, const float* __restrict__ w0,
    const float* __restrict__ w1, const float* __restrict__ w2,
    const float* __restrict__ w3,
    short* o0, short* o1, short* o2, short* o3, short* o4, short* o5, short* o6)
{
    const int y = blockIdx.y;
    const float* ins[7]  = {a0, a1, a2, w0, w1, w2, w3};
    short*       outs[7] = {o0, o1, o2, o3, o4, o5, o6};
    const int n8 = (y < 3) ? (int)((size_t)B_ * S_ * H_ / 8) : (int)((size_t)H_ * H_ / 8);
    const int i = blockIdx.x * 256 + threadIdx.x;
    if (i >= n8) return;
    const float4* p = (const float4*)ins[y] + (size_t)i * 2;
    float4 a = p[0], b = p[1];
    bf16x8 o;
    o[0] = f2bf(a.x); o[1] = f2bf(a.y); o[2] = f2bf(a.z); o[3] = f2bf(a.w);
    o[4] = f2bf(b.x); o[5] = f2bf(b.y); o[6] = f2bf(b.z); o[7] = f2bf(b.w);
    *(bf16x8*)(outs[y] + (size_t)i * 8) = o;
}

// ---------------------------------------------------------------------------
// Shared MFMA GEMM core: 128x128 tile, BK=64 (16 iters), 4 waves (2x2),
// wave = 64x64, K fixed at 1024. LDS 16 KB per matrix, global_load_lds
// width=16, XOR-swizzled chunks. UNCHANGED verified core.
// Computes acc[mi][ni] lane(l15,q4,r):
//   C[arow = m0+wm*64+mi*16+q4*4+r][brow = n0+wn*64+ni*16+l15]
//   = sum_k A[arow,k] * B[brow,k]
// ---------------------------------------------------------------------------
__device__ __forceinline__ void gemm_core(
    const short* __restrict__ A, const short* __restrict__ W,
    int m0, int n0, short* As, short* Ws, f32x4 acc[4][4])
{
    const int tid  = threadIdx.x;
    const int w    = tid >> 6;
    const int lane = tid & 63;
    const int l15  = lane & 15;
    const int q4   = lane >> 4;
    const int wm   = w >> 1;
    const int wn   = w & 1;
    const int K    = 1024;
    const int swz  = l15 & 7;

    const char* Abase = (const char*)A + (size_t)m0 * K * 2;
    const char* Wbase = (const char*)W + (size_t)n0 * K * 2;

    #pragma unroll
    for (int mi = 0; mi < 4; ++mi)
        #pragma unroll
        for (int ni = 0; ni < 4; ++ni)
            acc[mi][ni] = (f32x4){0.f, 0.f, 0.f, 0.f};

    for (int k0 = 0; k0 < K; k0 += 64) {
        __syncthreads();
        #pragma unroll
        for (int t = 0; t < 4; ++t) {
            const int ob  = t * 4096 + w * 1024;      // wave-uniform LDS base
            const int idx = t * 256 + w * 64 + lane;  // 16B-chunk 0..1023
            const int row = idx >> 3;
            const int sc  = (idx & 7) ^ (row & 7);    // swizzled source chunk
            gl_lds16(Abase + (size_t)row * (K * 2) + k0 * 2 + sc * 16, (char*)As + ob);
            gl_lds16(Wbase + (size_t)row * (K * 2) + k0 * 2 + sc * 16, (char*)Ws + ob);
        }
        __syncthreads();

        #pragma unroll
        for (int kh = 0; kh < 2; ++kh) {
            bf16x8 af[4], bf[4];
            #pragma unroll
            for (int mi = 0; mi < 4; ++mi)
                af[mi] = *(const bf16x8*)(As + (wm * 64 + mi * 16 + l15) * 64
                                             + (((kh * 4 + q4) ^ swz) * 8));
            #pragma unroll
            for (int ni = 0; ni < 4; ++ni)
                bf[ni] = *(const bf16x8*)(Ws + (wn * 64 + ni * 16 + l15) * 64
                                             + (((kh * 4 + q4) ^ swz) * 8));
            #pragma unroll
            for (int mi = 0; mi < 4; ++mi)
                #pragma unroll
                for (int ni = 0; ni < 4; ++ni)
                    acc[mi][ni] = __builtin_amdgcn_mfma_f32_16x16x32_bf16(
                        af[mi], bf[ni], acc[mi][ni], 0, 0, 0);
        }
    }
}

// ---------------------------------------------------------------------------
// Fused projection GEMMs (round-13: uniform SWAPPED call -- core-A = weights,
// core-B = activations for ALL z; lane then holds 4 CONSECUTIVE d for z0/z1
// -> b64 stores + cvt_pk epilogue instead of 64 scattered b16 + f2bf).
// z=0 -> q (scatter [B*NH,S,HS], scaled by QSCALE_), z=1 -> k (same),
// z=2 -> vT (transpose-scatter [B*NH,HS,S]; epilogue unchanged -- its fast
// output dim s is already lane-contiguous).
// ---------------------------------------------------------------------------
__global__ __launch_bounds__(256) void gemm_proj_k(
    const short* __restrict__ Aq, const short* __restrict__ Wqb,
    const float* __restrict__ bq, short* __restrict__ qb,
    const short* __restrict__ Ak, const short* __restrict__ Wkb,
    const float* __restrict__ bk, short* __restrict__ kb,
    const short* __restrict__ Wvb, const short* __restrict__ Av,
    const float* __restrict__ bv, short* __restrict__ vtb)
{
    __shared__ short As[128 * 64];   // 16 KB (weights side)
    __shared__ short Ws[128 * 64];   // 16 KB (activations side)

    const int z = blockIdx.z;
    const short *Wm, *Am; const float* bias; short* out;
    if (z == 0)      { Wm = Wqb; Am = Aq; bias = bq; out = qb;  }
    else if (z == 1) { Wm = Wkb; Am = Ak; bias = bk; out = kb;  }
    else             { Wm = Wvb; Am = Av; bias = bv; out = vtb; }
    const int m0 = blockIdx.y * 128;   // weight-row block (0..896)
    const int n0 = blockIdx.x * 128;   // activation-row block (0..8064)

    f32x4 acc[4][4];
    gemm_core(Wm, Am, m0, n0, As, Ws, acc);

    const int tid  = threadIdx.x;
    const int w    = tid >> 6;
    const int lane = tid & 63;
    const int l15  = lane & 15;
    const int q4   = lane >> 4;
    const int wm   = w >> 1;
    const int wn   = w & 1;

    if (z != 2) {
        // lane holds q/k[m = act row][n = mi*16+q4*4+r weight row]:
        // n gives (h = n>>6, d = n&63) with d 4-consecutive -> b64 stores.
        #pragma unroll
        for (int mi = 0; mi < 4; ++mi) {
            const int nbase = m0 + wm * 64 + mi * 16 + q4 * 4;
            const float4 b4 = *(const float4*)(bias + nbase);
            const int d0 = nbase & 63;
            const int h  = nbase >> 6;
            #pragma unroll
            for (int ni = 0; ni < 4; ++ni) {
                const int m = n0 + wn * 64 + ni * 16 + l15;
                const int bb = m >> 11, s = m & (S_ - 1);
                float v0 = acc[mi][ni][0] + b4.x;
                float v1 = acc[mi][ni][1] + b4.y;
                float v2 = acc[mi][ni][2] + b4.z;
                float v3 = acc[mi][ni][3] + b4.w;
                if (z == 0) { v0 *= QSCALE_; v1 *= QSCALE_; v2 *= QSCALE_; v3 *= QSCALE_; }
                unsigned lo, hi;
                asm("v_cvt_pk_bf16_f32 %0, %1, %2" : "=v"(lo) : "v"(v0), "v"(v1));
                asm("v_cvt_pk_bf16_f32 %0, %1, %2" : "=v"(hi) : "v"(v2), "v"(v3));
                uint2 pk; pk.x = lo; pk.y = hi;
                *(uint2*)(out + (((size_t)bb * NH_ + h) * S_ + s) * HS_ + d0) = pk;
            }
        }
    } else {
        // vT[(h,d) = weight row][s = act row]: s is lane-contiguous (l15).
        #pragma unroll
        for (int mi = 0; mi < 4; ++mi) {
            #pragma unroll
            for (int r = 0; r < 4; ++r) {
                const int m = m0 + wm * 64 + mi * 16 + q4 * 4 + r;  // weight row
                const float bm = bias[m];
                const int h = m >> 6, d = m & (HS_ - 1);
                #pragma unroll
                for (int ni = 0; ni < 4; ++ni) {
                    const int n = n0 + wn * 64 + ni * 16 + l15;     // act row
                    const int bb = n >> 11, s = n & (S_ - 1);
                    out[(((size_t)bb * NH_ + h) * HS_ + d) * S_ + s] =
                        f2bf(acc[mi][ni][r] + bm);
                }
            }
        }
    }
}

// ---------------------------------------------------------------------------
// Output-projection GEMM (swapped call): fp32 out = ctx @ Wo^T + bo with
// lane holding 4 consecutive n -> coalesced dwordx4 stores.
// ---------------------------------------------------------------------------
__global__ __launch_bounds__(256) void gemm_out_k(
    const short* __restrict__ Wo, const short* __restrict__ Cb,
    const float* __restrict__ bias, float* __restrict__ Cout)
{
    __shared__ short As[128 * 64];
    __shared__ short Ws[128 * 64];
    const int m0 = blockIdx.y * 128;   // weight-row block (n-space)
    const int n0 = blockIdx.x * 128;   // ctx-row block (m-space)

    f32x4 acc[4][4];
    gemm_core(Wo, Cb, m0, n0, As, Ws, acc);

    const int tid  = threadIdx.x;
    const int w    = tid >> 6;
    const int lane = tid & 63;
    const int l15  = lane & 15;
    const int q4   = lane >> 4;
    const int wm   = w >> 1;
    const int wn   = w & 1;

    #pragma unroll
    for (int mi = 0; mi < 4; ++mi) {
        const int nbase = m0 + wm * 64 + mi * 16 + q4 * 4;
        const float4 b4 = *(const float4*)(bias + nbase);
        #pragma unroll
        for (int ni = 0; ni < 4; ++ni) {
            const int m = n0 + wn * 64 + ni * 16 + l15;
            float4 vv;
            vv.x = acc[mi][ni][0] + b4.x;
            vv.y = acc[mi][ni][1] + b4.y;
            vv.z = acc[mi][ni][2] + b4.z;
            vv.w = acc[mi][ni][3] + b4.w;
            *(float4*)(Cout + (size_t)m * H_ + nbase) = vv;
        }
    }
}

// ---------------------------------------------------------------------------
// MFMA flash attention (r5 kernel, verified ~<100us) + round-13 change:
// XCD head-clustering blockIdx remap ONLY (mechanism verified r2: FETCH
// 147->25 MB). Structure, LDS staging, P-in-register PV: all unchanged.
// 512 blocks: flat f = by*8+bx; head = (f&7)*8 + ((f>>3)&7)  (XCD k serves
// heads 8k..8k+7 -> 4 MB K/V = one L2), qx = f>>6 (0..7), pass pairing
// {qx, 15-qx} as before.
// ---------------------------------------------------------------------------
__global__ __launch_bounds__(256) void attn_mfma(
    const short* __restrict__ Q, const short* __restrict__ K,
    const short* __restrict__ VT, short* __restrict__ O)
{
    __shared__ short Ks[2][64 * 64];     // [slot][key][d]  8 KB/slot, swizzled
    __shared__ short Vt[2][64 * 64];     // [slot][d][key]  8 KB/slot, swizzled

    const int tid  = threadIdx.x;
    const int w    = tid >> 6;
    const int lane = tid & 63;
    const int l15  = lane & 15;
    const int q4   = lane >> 4;
    const int swz  = l15 & 7;

    const int f   = blockIdx.y * 8 + blockIdx.x;       // dispatch-linear id
    const int bh  = (f & 7) * 8 + ((f >> 3) & 7);      // head-batch, XCD-clustered
    const int qx  = f >> 6;                            // 0..7 (pass pairing)

    const size_t base = (size_t)bh * S_ * HS_;
    const int b = bh >> 4;
    const int h = bh & 15;

    // stage kv-tile kt_ into LDS slot: async DMA, swizzled source chunks.
#define STAGE_KV(slot_, kt_)                                                      \
    do {                                                                          \
        _Pragma("unroll")                                                         \
        for (int t = 0; t < 2; ++t) {                                             \
            const int ob  = (slot_) * 8192 + t * 4096 + w * 1024;                 \
            const int idx = t * 256 + w * 64 + lane;   /* 16B-chunk 0..511 */     \
            const int r   = idx >> 3;                                             \
            const int sc  = (idx & 7) ^ (r & 7);       /* swizzled src chunk */   \
            gl_lds16(K + base + (size_t)((kt_) * 64 + r) * HS_ + sc * 8,          \
                     (char*)Ks + ob);                                             \
            gl_lds16(VT + base + (size_t)r * S_ + (kt_) * 64 + sc * 8,            \
                     (char*)Vt + ob);                                             \
        }                                                                         \
    } while (0)

    #pragma unroll 1
    for (int pass = 0; pass < 2; ++pass) {
        const int qt = pass ? (15 - qx) : qx;
        const int ktmax = 2 * qt + 1;

        // prologue: stage tile 0 into slot 0 (drained by the syncthreads below)
        STAGE_KV(0, 0);

        bf16x8 aQ[2][2];
        #pragma unroll
        for (int mi = 0; mi < 2; ++mi) {
            const int qrow = qt * 128 + w * 32 + mi * 16 + l15;
            #pragma unroll
            for (int kh = 0; kh < 2; ++kh)
                aQ[mi][kh] = *(const bf16x8*)(Q + base + (size_t)qrow * HS_ + kh * 32 + q4 * 8);
        }

        f32x4 accO[2][4];
        float lsum[2];
        #pragma unroll
        for (int mi = 0; mi < 2; ++mi) {
            #pragma unroll
            for (int db = 0; db < 4; ++db) accO[mi][db] = (f32x4){0.f, 0.f, 0.f, 0.f};
            lsum[mi] = 0.f;
        }

        __syncthreads();  // tile 0 resident

        for (int kt = 0; kt <= ktmax; ++kt) {
            const int cur = kt & 1;
            // issue next tile's loads NOW; they drain at this iter's barrier
            if (kt < ktmax) STAGE_KV(cur ^ 1, kt + 1);

            // S^T = K @ Q^T: lane (l15,q4) holds
            //   S[q = qt*128+w*32+mi*16+l15][key = kt*64+nb*16+q4*4+r]
            f32x4 sT[2][4];
            const short* KsBase = &Ks[cur][0];
            __builtin_amdgcn_s_setprio(1);
            #pragma unroll
            for (int nb = 0; nb < 4; ++nb) {
                const short* krow = KsBase + (nb * 16 + l15) * 64;
                bf16x8 k0 = *(const bf16x8*)(krow + ((q4 ^ swz) * 8));
                bf16x8 k1 = *(const bf16x8*)(krow + (((4 + q4) ^ swz) * 8));
                #pragma unroll
                for (int mi = 0; mi < 2; ++mi) {
                    f32x4 a = (f32x4){0.f, 0.f, 0.f, 0.f};
                    a = __builtin_amdgcn_mfma_f32_16x16x32_bf16(k0, aQ[mi][0], a, 0, 0, 0);
                    a = __builtin_amdgcn_mfma_f32_16x16x32_bf16(k1, aQ[mi][1], a, 0, 0, 0);
                    sT[mi][nb] = a;
                }
            }
            __builtin_amdgcn_s_setprio(0);

            // causal mask (wave-uniform trigger, last two tiles of the pass)
            if (kt >= 2 * qt) {
                #pragma unroll
                for (int mi = 0; mi < 2; ++mi) {
                    const int qrow = qt * 128 + w * 32 + mi * 16 + l15;
                    #pragma unroll
                    for (int nb = 0; nb < 4; ++nb)
                        #pragma unroll
                        for (int r = 0; r < 4; ++r) {
                            const int kj = kt * 64 + nb * 16 + q4 * 4 + r;
                            if (kj > qrow) sT[mi][nb][r] = -INFINITY;
                        }
                }
            }

            // p = exp2(s) (pre-scaled); accumulate l; pack PV A-fragments.
            bf16x8 aP[2][2];
            #pragma unroll
            for (int mi = 0; mi < 2; ++mi) {
                float p[4][4];
                #pragma unroll
                for (int nb = 0; nb < 4; ++nb)
                    #pragma unroll
                    for (int r = 0; r < 4; ++r) {
                        float pv;
                        asm("v_exp_f32 %0, %1" : "=v"(pv) : "v"(sT[mi][nb][r]));
                        lsum[mi] += pv;       // exp2(-inf)=0 for masked
                        p[nb][r] = pv;
                    }
                #pragma unroll
                for (int hf = 0; hf < 2; ++hf) {
                    unsigned w0, w1, w2, w3;
                    asm("v_cvt_pk_bf16_f32 %0, %1, %2" : "=v"(w0) : "v"(p[2*hf][0]),   "v"(p[2*hf][1]));
                    asm("v_cvt_pk_bf16_f32 %0, %1, %2" : "=v"(w1) : "v"(p[2*hf][2]),   "v"(p[2*hf][3]));
                    asm("v_cvt_pk_bf16_f32 %0, %1, %2" : "=v"(w2) : "v"(p[2*hf+1][0]), "v"(p[2*hf+1][1]));
                    asm("v_cvt_pk_bf16_f32 %0, %1, %2" : "=v"(w3) : "v"(p[2*hf+1][2]), "v"(p[2*hf+1][3]));
                    u32x4 pw; pw[0] = w0; pw[1] = w1; pw[2] = w2; pw[3] = w3;
                    aP[mi][hf] = __builtin_bit_cast(bf16x8, pw);
                }
            }

            // O += P @ V. V B-fragment read key-permuted from swizzled LDS.
            const short* VtBase = &Vt[cur][0];
            __builtin_amdgcn_s_setprio(1);
            #pragma unroll
            for (int db = 0; db < 4; ++db) {
                const short* vrow = VtBase + (db * 16 + l15) * 64;
                #pragma unroll
                for (int hf = 0; hf < 2; ++hf) {
                    const int lc0 = 4 * hf + (q4 >> 1);
                    const int lc1 = lc0 + 2;
                    s16x4 vlo = *(const s16x4*)(vrow + ((lc0 ^ swz) * 8) + 4 * (q4 & 1));
                    s16x4 vhi = *(const s16x4*)(vrow + ((lc1 ^ swz) * 8) + 4 * (q4 & 1));
                    bf16x8 vf = __builtin_shufflevector(vlo, vhi, 0, 1, 2, 3, 4, 5, 6, 7);
                    #pragma unroll
                    for (int mi = 0; mi < 2; ++mi)
                        accO[mi][db] = __builtin_amdgcn_mfma_f32_16x16x32_bf16(
                            aP[mi][hf], vf, accO[mi][db], 0, 0, 0);
                }
            }
            __builtin_amdgcn_s_setprio(0);

            // one barrier per tile: drains next-tile DMA + protects restage
            __syncthreads();
        }

        // epilogue: reduce lsum across q4 groups, normalize, write bf16 ctx.
        #pragma unroll
        for (int mi = 0; mi < 2; ++mi) {
            float ls = lsum[mi];
            ls += __shfl_xor(ls, 16);
            ls += __shfl_xor(ls, 32);
            #pragma unroll
            for (int r = 0; r < 4; ++r) {
                const float inv = 1.f / __shfl(ls, q4 * 4 + r);
                const int orow = qt * 128 + w * 32 + mi * 16 + q4 * 4 + r;
                short* op = O + ((size_t)(b * S_ + orow)) * H_ + h * HS_;
                #pragma unroll
                for (int db = 0; db < 4; ++db)
                    op[db * 16 + l15] = f2bf(accO[mi][db][r] * inv);
            }
        }
        // last loop iter ended in __syncthreads; epilogue touches no LDS.
    }
#undef STAGE_KV
}

// ---------------------------------------------------------------------------
extern "C" void kernel_launch(void* const* d_in, const int* in_sizes, int n_in,
                              void* d_out, int out_size, void* d_ws, size_t ws_size,
                              hipStream_t stream)
{
    const float* query = (const float*)d_in[0];
    const float* key   = (const float*)d_in[1];
    const float* value = (const float*)d_in[2];
    // d_in[3] = causal_mask: unused (causality computed from indices)
    const float* Wq = (const float*)d_in[4];
    const float* bq = (const float*)d_in[5];
    const float* Wk = (const float*)d_in[6];
    const float* bk = (const float*)d_in[7];
    const float* Wv = (const float*)d_in[8];
    const float* bv = (const float*)d_in[9];
    const float* Wo = (const float*)d_in[10];
    const float* bo = (const float*)d_in[11];
    float* out = (float*)d_out;

    const size_t EA = (size_t)B_ * S_ * H_;   // 8388608 activation elems
    const size_t EW = (size_t)H_ * H_;        // 1048576 weight elems

    short* Aq  = (short*)d_ws;        // bf16 inputs [M,K]
    short* Ak  = Aq  + EA;
    short* Av  = Ak  + EA;
    short* Wqb = Av  + EA;            // bf16 weights [N,K]
    short* Wkb = Wqb + EW;
    short* Wvb = Wkb + EW;
    short* Wob = Wvb + EW;
    short* qb  = Wob + EW;            // bf16 q (pre-scaled) [B*NH, S, HS]
    short* kb  = qb  + EA;
    short* vtb = kb  + EA;            // bf16 v TRANSPOSED [B*NH, HS, S]
    short* cb  = vtb + EA;            // bf16 ctx [B, S, H]

    const int M = B_ * S_;   // 8192

    cvt_all_k<<<dim3((int)(EA / 8 / 256), 7), 256, 0, stream>>>(
        query, key, value, Wq, Wk, Wv, Wo,
        Aq, Ak, Av, Wqb, Wkb, Wvb, Wob);

    gemm_proj_k<<<dim3(M / 128, H_ / 128, 3), 256, 0, stream>>>(
        Aq, Wqb, bq, qb, Ak, Wkb, bk, kb, Wvb, Av, bv, vtb);

    attn_mfma<<<dim3(S_ / 256, B_ * NH_), 256, 0, stream>>>(qb, kb, vtb, cb);

    gemm_out_k<<<dim3(M / 128, H_ / 128), 256, 0, stream>>>(Wob, cb, bo, out);
}